// Round 19
// baseline (428.352 us; speedup 1.0000x reference)
//
#include <hip/hip_runtime.h>
#include <math.h>

#define LOG2E 1.4426950408889634f

#if __has_builtin(__builtin_amdgcn_exp2f)
#define EXP2(x) __builtin_amdgcn_exp2f(x)
#else
#define EXP2(x) exp2f(x)
#endif

constexpr int B_ = 4, N_ = 2048, H_ = 4, D_ = 32, HD_ = 128;
constexpr int BH_ = B_ * H_;          // 16
constexpr int ROWS_ = BH_ * N_;       // 32768
constexpr size_t M_ = (size_t)ROWS_ * D_;  // 1,048,576 floats

typedef float v4f __attribute__((ext_vector_type(4)));
typedef _Float16 h2 __attribute__((ext_vector_type(2)));

// x[BN,K] @ Wl/Wr[K,128] + bl/br ->
//   xl   f32 [bh][n][d]      (k_u only)
//   xlh  f16 [bh][n][d]      (score)
//   xrh  f16 [bh][n][d]      (per-lane target rows)
//   xlpT f16 [bh][n/2][d]    (PV: j-pairs per d)
__global__ __launch_bounds__(256) void k_linear(
    const float* __restrict__ x,
    const float* __restrict__ Wl, const float* __restrict__ bl,
    const float* __restrict__ Wr, const float* __restrict__ br,
    float* __restrict__ xl, unsigned short* __restrict__ xlh,
    unsigned short* __restrict__ xrh, unsigned int* __restrict__ xlpT, int K)
{
    __shared__ __align__(16) float xs[32 * 128];
    const int tid = threadIdx.x;
    const int r0 = blockIdx.x * 32;
    const float4* src = (const float4*)(x + (size_t)r0 * K);
    float4* dst = (float4*)xs;
    for (int idx = tid; idx < 8 * K; idx += 256) dst[idx] = src[idx];
    __syncthreads();

    const int c  = tid & 127;
    const int rg = tid >> 7;
    float accl[16], accr[16];
    const float blv = bl[c], brv = br[c];
    #pragma unroll
    for (int r = 0; r < 16; r++) { accl[r] = blv; accr[r] = brv; }
    #pragma unroll 8
    for (int k = 0; k < K; k++) {
        const float wl = Wl[k * HD_ + c];
        const float wr = Wr[k * HD_ + c];
        #pragma unroll
        for (int r = 0; r < 16; r++) {
            const float xv = xs[(rg * 16 + r) * K + k];
            accl[r] = fmaf(xv, wl, accl[r]);
            accr[r] = fmaf(xv, wr, accr[r]);
        }
    }
    const int h = c >> 5, d = c & 31;
    #pragma unroll
    for (int r = 0; r < 16; r++) {
        const int row = r0 + rg * 16 + r;
        const int b = row >> 11, n = row & (N_ - 1);
        const size_t o = (((size_t)(b * H_ + h)) * N_ + n) * D_ + d;
        xl[o] = accl[r];
        xlh[o] = __builtin_bit_cast(unsigned short, (_Float16)accl[r]);
        xrh[o] = __builtin_bit_cast(unsigned short, (_Float16)accr[r]);
    }
    #pragma unroll
    for (int r = 0; r < 16; r += 2) {
        const int row = r0 + rg * 16 + r;
        const int b = row >> 11, n = row & (N_ - 1);
        h2 pr;
        pr.x = (_Float16)accl[r];
        pr.y = (_Float16)accl[r + 1];
        const size_t o = (((size_t)(b * H_ + h)) * (N_ / 2) + (n >> 1)) * D_ + d;
        xlpT[o] = __builtin_bit_cast(unsigned int, pr);
    }
}

// u_j = 0.6*log2e * att_h . xl_j  (target-side term cancels in softmax)
__global__ __launch_bounds__(256) void k_u(
    const float* __restrict__ xl, const float* __restrict__ att,
    float* __restrict__ u)
{
    const int idx = blockIdx.x * 256 + threadIdx.x; // [0, ROWS_)
    const int h = (idx / N_) & (H_ - 1);
    const float4* a4 = (const float4*)(att + h * D_);
    const float4* l4 = (const float4*)(xl + (size_t)idx * D_);
    float su = 0.f;
    #pragma unroll
    for (int q = 0; q < 8; q++) {
        const float4 a = a4[q], lv = l4[q];
        su += a.x * lv.x + a.y * lv.y + a.z * lv.z + a.w * lv.w;
    }
    u[idx] = 0.6f * LOG2E * su;
}

// Per-row sound upper bound on e (log2 domain); also packs tch.
// EXACT R15 version (passed at absmax 0.0156) - no numeric changes.
__global__ __launch_bounds__(512) void k_bound(
    const unsigned int* __restrict__ xlh, const unsigned int* __restrict__ xrh,
    const float* __restrict__ u, const float* __restrict__ att,
    float* __restrict__ bound, unsigned int* __restrict__ tch)
{
    __shared__ float redA[16][33];
    __shared__ float redB[16][33];
    __shared__ float clv[32];
    __shared__ float tca[32];
    __shared__ float redu[512];
    const int bh = blockIdx.x, h = bh & (H_ - 1), t = threadIdx.x;

    if (bh < H_ && t < 16) {
        h2 v;
        v.x = (_Float16)(att[bh * D_ + 2 * t]     * (0.4f * LOG2E));
        v.y = (_Float16)(att[bh * D_ + 2 * t + 1] * (0.4f * LOG2E));
        tch[bh * 16 + t] = __builtin_bit_cast(unsigned int, v);
    }
    if (t < 16) {
        _Float16 a = (_Float16)(att[h * D_ + 2 * t]     * (0.4f * LOG2E));
        _Float16 b = (_Float16)(att[h * D_ + 2 * t + 1] * (0.4f * LOG2E));
        tca[2 * t]     = fabsf((float)a);
        tca[2 * t + 1] = fabsf((float)b);
    }
    const unsigned int* xb = xlh + (size_t)bh * N_ * 16;
    const int p = t & 15, rg = t >> 4;
    float m0 = 0.f, m1 = 0.f;
    for (int r = rg; r < N_; r += 32) {
        h2 z = __builtin_bit_cast(h2, xb[r * 16 + p] & 0x7FFF7FFFu);
        m0 = fmaxf(m0, (float)z.x);
        m1 = fmaxf(m1, (float)z.y);
    }
    redA[p][rg] = m0; redB[p][rg] = m1;
    const float* ub = u + (size_t)bh * N_;
    float um = -1e30f;
    for (int r = t; r < N_; r += 512) um = fmaxf(um, ub[r]);
    redu[t] = um;
    __syncthreads();
    if (t < 16) {
        float a = 0.f, b = 0.f;
        for (int g = 0; g < 32; g++) { a = fmaxf(a, redA[t][g]); b = fmaxf(b, redB[t][g]); }
        clv[2 * t] = a; clv[2 * t + 1] = b;
    }
    for (int s = 256; s > 0; s >>= 1) {
        if (t < s) redu[t] = fmaxf(redu[t], redu[t + s]);
        __syncthreads();
    }
    const float umax = redu[0];
    const unsigned int* xrb = xrh + (size_t)bh * N_ * 16;
    for (int r = t; r < N_; r += 512) {
        float s = 0.f;
        #pragma unroll
        for (int k = 0; k < 16; k++) {
            h2 z = __builtin_bit_cast(h2, xrb[r * 16 + k] & 0x7FFF7FFFu);
            s += tca[2 * k] * (clv[2 * k] + (float)z.x)
               + tca[2 * k + 1] * (clv[2 * k + 1] + (float)z.y);
        }
        bound[bh * N_ + r] = umax + s + 0.25f;
    }
}

// Monolithic asm blocks, EXACT R15 instruction sequences (passed, absmax
// 0.0156). 2-ROWS-PER-LANE: each lane owns rows i and i+256. Per-row math
// (j order, op order) is bit-identical to R15 -> absmax unchanged. Waves
// halve, so the wave-uniform LDS broadcast traffic (the R15 bottleneck:
// 17 ds_read_b128/jp x 64-lane replication) is HALVED per unit work.

#define G(K, EA, EB)                                              \
    "v_pk_add_f16 %[z0], %[a" K "], %[x" K "]\n\t"                \
    "v_pk_add_f16 %[z1], %[b" K "], %[x" K "]\n\t"                \
    "v_and_b32 %[z0], %[mk], %[z0]\n\t"                           \
    "v_and_b32 %[z1], %[mk], %[z1]\n\t"                           \
    "v_dot2_f32_f16 %[" EA "], %[z0], %[t" K "], %[" EA "]\n\t"   \
    "v_dot2_f32_f16 %[" EB "], %[z1], %[t" K "], %[" EB "]\n\t"

#define DOT(K) "v_dot2_f32_f16 %[o" K "], %[p], %[v" K "], %[o" K "]\n\t"

#define SCORE_ASM(E0, F0, E1, F1, XR)                                          \
    asm(G("0",  "e0", "e1") G("1",  "f0", "f1")                                \
        G("2",  "e0", "e1") G("3",  "f0", "f1")                                \
        G("4",  "e0", "e1") G("5",  "f0", "f1")                                \
        G("6",  "e0", "e1") G("7",  "f0", "f1")                                \
        G("8",  "e0", "e1") G("9",  "f0", "f1")                                \
        G("10", "e0", "e1") G("11", "f0", "f1")                                \
        G("12", "e0", "e1") G("13", "f0", "f1")                                \
        G("14", "e0", "e1") G("15", "f0", "f1")                                \
        : [e0]"+v"(E0), [f0]"+v"(F0), [e1]"+v"(E1), [f1]"+v"(F1),              \
          [z0]"=&v"(zz0), [z1]"=&v"(zz1)                                       \
        : [a0]"v"(S0.x),  [a1]"v"(S0.y),  [a2]"v"(S0.z),  [a3]"v"(S0.w),       \
          [a4]"v"(S1.x),  [a5]"v"(S1.y),  [a6]"v"(S1.z),  [a7]"v"(S1.w),       \
          [a8]"v"(S2.x),  [a9]"v"(S2.y),  [a10]"v"(S2.z), [a11]"v"(S2.w),      \
          [a12]"v"(S3.x), [a13]"v"(S3.y), [a14]"v"(S3.z), [a15]"v"(S3.w),      \
          [b0]"v"(S4.x),  [b1]"v"(S4.y),  [b2]"v"(S4.z),  [b3]"v"(S4.w),       \
          [b4]"v"(S5.x),  [b5]"v"(S5.y),  [b6]"v"(S5.z),  [b7]"v"(S5.w),       \
          [b8]"v"(S6.x),  [b9]"v"(S6.y),  [b10]"v"(S6.z), [b11]"v"(S6.w),      \
          [b12]"v"(S7.x), [b13]"v"(S7.y), [b14]"v"(S7.z), [b15]"v"(S7.w),      \
          [x0]"v"(XR[0]),   [x1]"v"(XR[1]),   [x2]"v"(XR[2]),   [x3]"v"(XR[3]),\
          [x4]"v"(XR[4]),   [x5]"v"(XR[5]),   [x6]"v"(XR[6]),   [x7]"v"(XR[7]),\
          [x8]"v"(XR[8]),   [x9]"v"(XR[9]),   [x10]"v"(XR[10]), [x11]"v"(XR[11]),\
          [x12]"v"(XR[12]), [x13]"v"(XR[13]), [x14]"v"(XR[14]), [x15]"v"(XR[15]),\
          [t0]"s"(tcs[0]),   [t1]"s"(tcs[1]),   [t2]"s"(tcs[2]),   [t3]"s"(tcs[3]),\
          [t4]"s"(tcs[4]),   [t5]"s"(tcs[5]),   [t6]"s"(tcs[6]),   [t7]"s"(tcs[7]),\
          [t8]"s"(tcs[8]),   [t9]"s"(tcs[9]),   [t10]"s"(tcs[10]), [t11]"s"(tcs[11]),\
          [t12]"s"(tcs[12]), [t13]"s"(tcs[13]), [t14]"s"(tcs[14]), [t15]"s"(tcs[15]),\
          [mk]"s"(kAbsMask))

#define PV_ASM(L, O, P01)                                                      \
    asm("v_dot2_f32_f16 %[l], %[p], %[on], %[l]\n\t"                           \
        DOT("0")  DOT("1")  DOT("2")  DOT("3")                                 \
        DOT("4")  DOT("5")  DOT("6")  DOT("7")                                 \
        DOT("8")  DOT("9")  DOT("10") DOT("11")                                \
        DOT("12") DOT("13") DOT("14") DOT("15")                                \
        DOT("16") DOT("17") DOT("18") DOT("19")                                \
        DOT("20") DOT("21") DOT("22") DOT("23")                                \
        DOT("24") DOT("25") DOT("26") DOT("27")                                \
        DOT("28") DOT("29") DOT("30") DOT("31")                                \
        : [l]"+v"(L),                                                          \
          [o0]"+v"(O[0]),   [o1]"+v"(O[1]),   [o2]"+v"(O[2]),   [o3]"+v"(O[3]),\
          [o4]"+v"(O[4]),   [o5]"+v"(O[5]),   [o6]"+v"(O[6]),   [o7]"+v"(O[7]),\
          [o8]"+v"(O[8]),   [o9]"+v"(O[9]),   [o10]"+v"(O[10]), [o11]"+v"(O[11]),\
          [o12]"+v"(O[12]), [o13]"+v"(O[13]), [o14]"+v"(O[14]), [o15]"+v"(O[15]),\
          [o16]"+v"(O[16]), [o17]"+v"(O[17]), [o18]"+v"(O[18]), [o19]"+v"(O[19]),\
          [o20]"+v"(O[20]), [o21]"+v"(O[21]), [o22]"+v"(O[22]), [o23]"+v"(O[23]),\
          [o24]"+v"(O[24]), [o25]"+v"(O[25]), [o26]"+v"(O[26]), [o27]"+v"(O[27]),\
          [o28]"+v"(O[28]), [o29]"+v"(O[29]), [o30]"+v"(O[30]), [o31]"+v"(O[31])\
        : [p]"v"(P01), [on]"s"(kOnes),                                         \
          [v0]"v"(V0.x),  [v1]"v"(V0.y),  [v2]"v"(V0.z),  [v3]"v"(V0.w),       \
          [v4]"v"(V1.x),  [v5]"v"(V1.y),  [v6]"v"(V1.z),  [v7]"v"(V1.w),       \
          [v8]"v"(V2.x),  [v9]"v"(V2.y),  [v10]"v"(V2.z), [v11]"v"(V2.w),      \
          [v12]"v"(V3.x), [v13]"v"(V3.y), [v14]"v"(V3.z), [v15]"v"(V3.w),      \
          [v16]"v"(V4.x), [v17]"v"(V4.y), [v18]"v"(V4.z), [v19]"v"(V4.w),      \
          [v20]"v"(V5.x), [v21]"v"(V5.y), [v22]"v"(V5.z), [v23]"v"(V5.w),      \
          [v24]"v"(V6.x), [v25]"v"(V6.y), [v26]"v"(V6.z), [v27]"v"(V6.w),      \
          [v28]"v"(V7.x), [v29]"v"(V7.y), [v30]"v"(V7.z), [v31]"v"(V7.w))

__global__ __launch_bounds__(256) void k_attn(
    const unsigned int* __restrict__ xlh,   // [bh][n][16] u32 (d-pairs)
    const unsigned int* __restrict__ xlpT,  // [bh][n/2][32] u32 (j-pairs)
    const unsigned int* __restrict__ xrh,
    const float* __restrict__ u, const float* __restrict__ bound,
    const unsigned int* __restrict__ tch,
    float* __restrict__ P, float* __restrict__ lb, int jlen)
{
    __shared__ __align__(16) uint4 s_xlh[1024];   // 256 j-rows x 4 uint4
    __shared__ __align__(16) uint4 s_xlt[1024];   // 128 jp x 8 uint4
    __shared__ float s_u[256];
    const int tid = threadIdx.x;
    const int t64 = blockIdx.x & 63, part = blockIdx.x >> 6;
    const int bh = t64 >> 2;
    const int h  = bh & (H_ - 1);
    const int rowA = bh * N_ + (t64 & 3) * 512 + tid;   // lane's first row
    const int rowB = rowA + 256;                        // lane's second row

    unsigned int tcs[16];
    #pragma unroll
    for (int k = 0; k < 16; k++)
        tcs[k] = __builtin_amdgcn_readfirstlane(tch[h * 16 + k]);

    unsigned int xra[16], xrb[16];
    {
        const uint4* s = (const uint4*)(xrh + (size_t)rowA * 16);
        const uint4 a = s[0], b = s[1], c = s[2], d = s[3];
        xra[0]=a.x; xra[1]=a.y; xra[2]=a.z; xra[3]=a.w;
        xra[4]=b.x; xra[5]=b.y; xra[6]=b.z; xra[7]=b.w;
        xra[8]=c.x; xra[9]=c.y; xra[10]=c.z; xra[11]=c.w;
        xra[12]=d.x; xra[13]=d.y; xra[14]=d.z; xra[15]=d.w;
    }
    {
        const uint4* s = (const uint4*)(xrh + (size_t)rowB * 16);
        const uint4 a = s[0], b = s[1], c = s[2], d = s[3];
        xrb[0]=a.x; xrb[1]=a.y; xrb[2]=a.z; xrb[3]=a.w;
        xrb[4]=b.x; xrb[5]=b.y; xrb[6]=b.z; xrb[7]=b.w;
        xrb[8]=c.x; xrb[9]=c.y; xrb[10]=c.z; xrb[11]=c.w;
        xrb[12]=d.x; xrb[13]=d.y; xrb[14]=d.z; xrb[15]=d.w;
    }
    const float negbA = 12.0f - bound[rowA];
    const float negbB = 12.0f - bound[rowB];
    const unsigned int kOnes = 0x3C003C00u;
    const unsigned int kAbsMask = 0x7FFF7FFFu;

    float lA = 0.f, lB = 0.f;
    float oA[32], oB[32];
    #pragma unroll
    for (int k = 0; k < 32; k++) { oA[k] = 0.f; oB[k] = 0.f; }

    const uint4* gx = (const uint4*)(xlh + (size_t)bh * N_ * 16);
    const uint4* gv = (const uint4*)(xlpT + (size_t)bh * (N_ / 2) * 32);
    const float* u_b = u + (size_t)bh * N_;

    const int jbeg = part * jlen;
    for (int jt = 0; jt < jlen; jt += 256) {
        if (jt) __syncthreads();
        const int j0 = jbeg + jt;
        #pragma unroll
        for (int k = 0; k < 4; k++)
            s_xlh[tid + 256 * k] = gx[(size_t)j0 * 4 + tid + 256 * k];
        #pragma unroll
        for (int k = 0; k < 4; k++)
            s_xlt[tid + 256 * k] = gv[(size_t)(j0 >> 1) * 8 + tid + 256 * k];
        s_u[tid] = u_b[j0 + tid];
        __syncthreads();

        for (int ljp = 0; ljp < 128; ljp++) {
            const uint4 S0 = s_xlh[8 * ljp + 0], S1 = s_xlh[8 * ljp + 1];
            const uint4 S2 = s_xlh[8 * ljp + 2], S3 = s_xlh[8 * ljp + 3];
            const uint4 S4 = s_xlh[8 * ljp + 4], S5 = s_xlh[8 * ljp + 5];
            const uint4 S6 = s_xlh[8 * ljp + 6], S7 = s_xlh[8 * ljp + 7];
            unsigned int zz0, zz1;
            // row A scores (bit-identical sequence to R15)
            float e0a = s_u[2 * ljp] + negbA, f0a = 0.f;
            float e1a = s_u[2 * ljp + 1] + negbA, f1a = 0.f;
            SCORE_ASM(e0a, f0a, e1a, f1a, xra);
            // row B scores
            float e0b = s_u[2 * ljp] + negbB, f0b = 0.f;
            float e1b = s_u[2 * ljp + 1] + negbB, f1b = 0.f;
            SCORE_ASM(e0b, f0b, e1b, f1b, xrb);

            const float p0a = EXP2(e0a + f0a);
            const float p1a = EXP2(e1a + f1a);
            const unsigned int p01a = __builtin_bit_cast(unsigned int,
                __builtin_amdgcn_cvt_pkrtz(p0a, p1a));
            const float p0b = EXP2(e0b + f0b);
            const float p1b = EXP2(e1b + f1b);
            const unsigned int p01b = __builtin_bit_cast(unsigned int,
                __builtin_amdgcn_cvt_pkrtz(p0b, p1b));

            const uint4 V0 = s_xlt[8 * ljp + 0], V1 = s_xlt[8 * ljp + 1];
            const uint4 V2 = s_xlt[8 * ljp + 2], V3 = s_xlt[8 * ljp + 3];
            const uint4 V4 = s_xlt[8 * ljp + 4], V5 = s_xlt[8 * ljp + 5];
            const uint4 V6 = s_xlt[8 * ljp + 6], V7 = s_xlt[8 * ljp + 7];
            PV_ASM(lA, oA, p01a);
            PV_ASM(lB, oB, p01b);
        }
    }

    {
        float* Pp = P + (size_t)part * M_ + (size_t)rowA * D_;
        #pragma unroll
        for (int k = 0; k < 8; k++) {
            v4f w;
            w.x = oA[4*k]; w.y = oA[4*k+1]; w.z = oA[4*k+2]; w.w = oA[4*k+3];
            ((v4f*)Pp)[k] = w;
        }
        lb[part * ROWS_ + rowA] = lA;
    }
    {
        float* Pp = P + (size_t)part * M_ + (size_t)rowB * D_;
        #pragma unroll
        for (int k = 0; k < 8; k++) {
            v4f w;
            w.x = oB[4*k]; w.y = oB[4*k+1]; w.z = oB[4*k+2]; w.w = oB[4*k+3];
            ((v4f*)Pp)[k] = w;
        }
        lb[part * ROWS_ + rowB] = lB;
    }
}

// Fused: merge JS partials (shared bound -> sum(o)/sum(l)) + bias + LN(128)
// (+optional ReLU). One 64-thread block per node row (b,n).
template <int JS>
__global__ __launch_bounds__(64) void k_comb_ln(
    const float* __restrict__ P, const float* __restrict__ lb,
    const float* __restrict__ bias, const float* __restrict__ g,
    const float* __restrict__ bta, float* __restrict__ outp, int do_relu)
{
    const int row = blockIdx.x;                    // b*N+n
    const int b = row >> 11, n = row & (N_ - 1);
    const int t = threadIdx.x;
    const int c0 = t, c1 = t + 64;
    const int bh0 = b * H_ + (c0 >> 5), bh1 = b * H_ + (c1 >> 5);
    const size_t i0 = ((size_t)bh0 * N_ + n) * D_ + (c0 & 31);
    const size_t i1 = ((size_t)bh1 * N_ + n) * D_ + (c1 & 31);
    float a0 = 0.f, a1 = 0.f, L0 = 0.f, L1 = 0.f;
    #pragma unroll
    for (int s = 0; s < JS; s++) {
        a0 += P[(size_t)s * M_ + i0];
        a1 += P[(size_t)s * M_ + i1];
        L0 += lb[s * ROWS_ + bh0 * N_ + n];
        L1 += lb[s * ROWS_ + bh1 * N_ + n];
    }
    const float x0 = a0 / L0 + bias[c0];
    const float x1 = a1 / L1 + bias[c1];
    float s = x0 + x1;
    #pragma unroll
    for (int w = 1; w < 64; w <<= 1) s += __shfl_xor(s, w);
    const float mu = s * (1.f / 128.f);
    const float d0 = x0 - mu, d1 = x1 - mu;
    float q = d0 * d0 + d1 * d1;
    #pragma unroll
    for (int w = 1; w < 64; w <<= 1) q += __shfl_xor(q, w);
    const float rstd = rsqrtf(q * (1.f / 128.f) + 1e-5f);
    float y0 = d0 * rstd * g[c0] + bta[c0];
    float y1 = d1 * rstd * g[c1] + bta[c1];
    if (do_relu) { y0 = fmaxf(y0, 0.f); y1 = fmaxf(y1, 0.f); }
    outp[(size_t)row * HD_ + c0] = y0;
    outp[(size_t)row * HD_ + c1] = y1;
}

extern "C" void kernel_launch(void* const* d_in, const int* in_sizes, int n_in,
                              void* d_out, int out_size, void* d_ws, size_t ws_size,
                              hipStream_t stream) {
    const float* x    = (const float*)d_in[0];
    const float* Wl1  = (const float*)d_in[2];
    const float* bl1  = (const float*)d_in[3];
    const float* Wr1  = (const float*)d_in[4];
    const float* br1  = (const float*)d_in[5];
    const float* att1 = (const float*)d_in[6];
    const float* bias1= (const float*)d_in[7];
    const float* ln1g = (const float*)d_in[8];
    const float* ln1b = (const float*)d_in[9];
    const float* Wl2  = (const float*)d_in[10];
    const float* bl2  = (const float*)d_in[11];
    const float* Wr2  = (const float*)d_in[12];
    const float* br2  = (const float*)d_in[13];
    const float* att2 = (const float*)d_in[14];
    const float* bias2= (const float*)d_in[15];
    const float* ln2g = (const float*)d_in[16];
    const float* ln2b = (const float*)d_in[17];

    float* ws = (float*)d_ws;
    float* xl = ws;                                   // M_
    unsigned short* xlh = (unsigned short*)(xl + M_); // M_ halfs
    unsigned short* xrh = xlh + M_;                   // M_ halfs
    unsigned int* xlpT = (unsigned int*)(xrh + M_);   // M_/2 u32
    float* u     = xl + (size_t)(2.5 * M_);           // ROWS_
    float* bound = u + ROWS_;                         // ROWS_
    unsigned int* tch = (unsigned int*)(bound + ROWS_); // 64 u32

    // j-split: largest fitting. floats = 2.5M + 2R + 64 + js*(M+R) + M (h slab)
    int js = 1;
    for (int cand = 8; cand >= 1; cand >>= 1) {
        const size_t need = ((size_t)(3.5 * M_) + 2 * ROWS_ + 64
                             + (size_t)cand * (M_ + ROWS_)) * sizeof(float);
        if (ws_size >= need) { js = cand; break; }
    }
    const int jlen = N_ / js;

    float* P  = (float*)(tch + 64);        // js * M_
    float* lb = P + (size_t)js * M_;       // js * ROWS_
    float* h  = lb + (size_t)js * ROWS_;   // M_ (dedicated slab)
    float* outf = (float*)d_out;

    const int BN = B_ * N_;                // 8192
    // ---- layer 1 ----
    k_linear<<<BN / 32, 256, 0, stream>>>(x, Wl1, bl1, Wr1, br1, xl, xlh, xrh, xlpT, 32);
    k_u<<<ROWS_ / 256, 256, 0, stream>>>(xl, att1, u);
    k_bound<<<BH_, 512, 0, stream>>>((const unsigned int*)xlh, (const unsigned int*)xrh,
                                     u, att1, bound, tch);
    k_attn<<<64 * js, 256, 0, stream>>>((const unsigned int*)xlh, xlpT,
                                        (const unsigned int*)xrh, u, bound, tch, P, lb, jlen);
    if      (js == 8) k_comb_ln<8><<<BN, 64, 0, stream>>>(P, lb, bias1, ln1g, ln1b, h, 1);
    else if (js == 4) k_comb_ln<4><<<BN, 64, 0, stream>>>(P, lb, bias1, ln1g, ln1b, h, 1);
    else if (js == 2) k_comb_ln<2><<<BN, 64, 0, stream>>>(P, lb, bias1, ln1g, ln1b, h, 1);
    else              k_comb_ln<1><<<BN, 64, 0, stream>>>(P, lb, bias1, ln1g, ln1b, h, 1);
    // ---- layer 2 ----
    k_linear<<<BN / 32, 256, 0, stream>>>(h, Wl2, bl2, Wr2, br2, xl, xlh, xrh, xlpT, 128);
    k_u<<<ROWS_ / 256, 256, 0, stream>>>(xl, att2, u);
    k_bound<<<BH_, 512, 0, stream>>>((const unsigned int*)xlh, (const unsigned int*)xrh,
                                     u, att2, bound, tch);
    k_attn<<<64 * js, 256, 0, stream>>>((const unsigned int*)xlh, xlpT,
                                        (const unsigned int*)xrh, u, bound, tch, P, lb, jlen);
    if      (js == 8) k_comb_ln<8><<<BN, 64, 0, stream>>>(P, lb, bias2, ln2g, ln2b, outf, 0);
    else if (js == 4) k_comb_ln<4><<<BN, 64, 0, stream>>>(P, lb, bias2, ln2g, ln2b, outf, 0);
    else if (js == 2) k_comb_ln<2><<<BN, 64, 0, stream>>>(P, lb, bias2, ln2g, ln2b, outf, 0);
    else              k_comb_ln<1><<<BN, 64, 0, stream>>>(P, lb, bias2, ln2g, ln2b, outf, 0);
}